// Round 1
// baseline (7967.883 us; speedup 1.0000x reference)
//
#include <hip/hip_runtime.h>
#include <hip/hip_bf16.h>
#include <math.h>

// Problem constants
#define BB   64      // batch
#define TT   512     // time steps
#define UU   350     // units per direction
#define GG   1050    // 3*UU gate columns
#define DCH  50
#define DWD  300
#define DIN  350     // DCH + DWD
#define CT   64      // time-chunk for xg staging
#define NCH  8       // TT / CT

// ---------------- ws layout (bytes) ----------------
// hbuf : [2 buf][2 dir][350 u][64 b] f32          = 358,400 B
// WhT  : [2 dir][1050 g][350 u] f32               = 2,940,000 B
// xg   : [2 dir][64 tloc][1050 g][64 b] f32       = 34,406,400 B
#define HBUF_OFF 0
#define HBUF_BYTES (2*2*UU*BB*4)
#define WHT_OFF  HBUF_BYTES
#define WHT_BYTES (2*GG*UU*4)
#define XG_OFF   3298560   // 256B-aligned past HBUF+WHT
#define XG_BYTES (2*CT*GG*BB*4)

// Transpose Wh -> WhT[dir][g][u] so the step kernel's weight reads are
// wave-uniform contiguous (scalar-load friendly).
__global__ __launch_bounds__(256) void wht_kernel(
    const float* __restrict__ Whf, const float* __restrict__ Whb,
    float* __restrict__ WhT)
{
    int idx = blockIdx.x * 256 + threadIdx.x;
    if (idx >= 2 * UU * GG) return;
    int dir = idx / (UU * GG);
    int r   = idx % (UU * GG);
    int u   = r / GG;
    int g   = r % GG;                 // consecutive lanes -> consecutive g: coalesced read
    const float* src = dir ? Whb : Whf;
    WhT[((size_t)dir * GG + g) * UU + u] = src[u * GG + g];
}

// xg GEMM for one time-chunk: xg[dir][tloc][g][b] = sum_k x[b,t,k]*Wx[k,g] + b0[g]
// 64g x 64b tile per block, K staged in 16-slabs through LDS.
__global__ __launch_bounds__(256) void xg_gemm_kernel(
    const float* __restrict__ ce, const float* __restrict__ we,
    const float* __restrict__ Wxf, const float* __restrict__ Wxb,
    const float* __restrict__ bf,  const float* __restrict__ bb,
    float* __restrict__ xg, int c)
{
    const int dir   = blockIdx.z;
    const int tloc  = blockIdx.y;
    const int gbase = blockIdx.x * 64;
    const int t     = dir ? (448 - c * CT + tloc) : (c * CT + tloc);
    const float* __restrict__ Wx   = dir ? Wxb : Wxf;
    const float* __restrict__ bias = dir ? bb  : bf;

    __shared__ float xs[16][68];   // [kk][b], padded to kill bank conflicts, 16B-aligned rows
    __shared__ float wsh[16][68];  // [kk][g]

    const int tid = threadIdx.x;
    const int b0 = (tid & 15) * 4;
    const int g0 = (tid >> 4) * 4;
    float acc[4][4] = {};          // [gi][bi]

    for (int k0 = 0; k0 < DIN; k0 += 16) {
        // stage x slab: e -> (b = e>>4, kk = e&15); 16-lane runs read 16 consecutive k of one b-row
        #pragma unroll
        for (int j = 0; j < 4; ++j) {
            int e = j * 256 + tid;
            int bbi = e >> 4, kk = e & 15;
            int k = k0 + kk;
            float v = 0.f;
            if (k < DIN)
                v = (k < DCH) ? ce[((size_t)bbi * TT + t) * DCH + k]
                              : we[((size_t)bbi * TT + t) * DWD + (k - DCH)];
            xs[kk][bbi] = v;
        }
        // stage W slab: e -> (kk = e>>6, gg = e&63); lanes sweep g: coalesced
        #pragma unroll
        for (int j = 0; j < 4; ++j) {
            int e = j * 256 + tid;
            int kk = e >> 6, gg = e & 63;
            int k = k0 + kk, g = gbase + gg;
            float v = 0.f;
            if (k < DIN && g < GG) v = Wx[(size_t)k * GG + g];
            wsh[kk][gg] = v;
        }
        __syncthreads();
        #pragma unroll
        for (int kk = 0; kk < 16; ++kk) {
            float4 xa = *(const float4*)&xs[kk][b0];
            float4 wa = *(const float4*)&wsh[kk][g0];
            acc[0][0] = fmaf(wa.x, xa.x, acc[0][0]);
            acc[0][1] = fmaf(wa.x, xa.y, acc[0][1]);
            acc[0][2] = fmaf(wa.x, xa.z, acc[0][2]);
            acc[0][3] = fmaf(wa.x, xa.w, acc[0][3]);
            acc[1][0] = fmaf(wa.y, xa.x, acc[1][0]);
            acc[1][1] = fmaf(wa.y, xa.y, acc[1][1]);
            acc[1][2] = fmaf(wa.y, xa.z, acc[1][2]);
            acc[1][3] = fmaf(wa.y, xa.w, acc[1][3]);
            acc[2][0] = fmaf(wa.z, xa.x, acc[2][0]);
            acc[2][1] = fmaf(wa.z, xa.y, acc[2][1]);
            acc[2][2] = fmaf(wa.z, xa.z, acc[2][2]);
            acc[2][3] = fmaf(wa.z, xa.w, acc[2][3]);
            acc[3][0] = fmaf(wa.w, xa.x, acc[3][0]);
            acc[3][1] = fmaf(wa.w, xa.y, acc[3][1]);
            acc[3][2] = fmaf(wa.w, xa.z, acc[3][2]);
            acc[3][3] = fmaf(wa.w, xa.w, acc[3][3]);
        }
        __syncthreads();
    }
    float* outp = xg + (size_t)((dir * CT + tloc) * GG) * BB;
    #pragma unroll
    for (int i = 0; i < 4; ++i) {
        int g = gbase + g0 + i;
        if (g < GG) {
            float bv = bias[g];
            float4 v;
            v.x = acc[i][0] + bv; v.y = acc[i][1] + bv;
            v.z = acc[i][2] + bv; v.w = acc[i][3] + bv;
            *(float4*)&outp[(size_t)g * BB + b0] = v;
        }
    }
}

// One recurrence step for both directions. Block = 64 batches x 4 units.
// Thread (b, u') computes all three gates (z,r,h) for its unit: the h_new
// combine is thread-local (no LDS, no barrier). Weight reads are wave-uniform
// (readfirstlane) -> scalar loads; h reads are lane-coalesced (256B rows).
__global__ __launch_bounds__(256) void gru_step_kernel(
    const float* __restrict__ xg, const float* __restrict__ WhT,
    const float* __restrict__ bf, const float* __restrict__ bb,
    const int* __restrict__ seqlen, float* __restrict__ hbuf,
    float* __restrict__ hid, int s, int c)
{
    const int b = threadIdx.x & 63;
    int up = __builtin_amdgcn_readfirstlane((int)(threadIdx.x >> 6)) + blockIdx.x * 4;
    if (up >= UU) return;
    const int dir    = blockIdx.y;
    const int slocal = s - c * CT;
    const int t      = dir ? (TT - 1 - s) : s;
    const int tloc   = dir ? (CT - 1 - slocal) : slocal;
    const float* __restrict__ bias = dir ? bb : bf;   // [2,1050]; b1 at +1050

    const float* __restrict__ hR = hbuf + (size_t)(((s & 1) * 2) + dir) * (UU * BB);
    float* __restrict__       hW = hbuf + (size_t)((((s & 1) ^ 1) * 2) + dir) * (UU * BB);

    const float* __restrict__ wz = WhT + ((size_t)dir * GG + up) * UU;
    const float* __restrict__ wr = WhT + ((size_t)dir * GG + UU + up) * UU;
    const float* __restrict__ wh = WhT + ((size_t)dir * GG + 2 * UU + up) * UU;

    float hz = bias[GG + up];
    float hr = bias[GG + UU + up];
    float hc = bias[GG + 2 * UU + up];

    #pragma unroll 10
    for (int u = 0; u < UU; ++u) {
        float hv = hR[u * BB + b];
        hz = fmaf(hv, wz[u], hz);
        hr = fmaf(hv, wr[u], hr);
        hc = fmaf(hv, wh[u], hc);
    }

    const float* xgp = xg + (size_t)((dir * CT + tloc) * GG) * BB;
    float xz = xgp[(size_t)(up)           * BB + b];
    float xr = xgp[(size_t)(up + UU)      * BB + b];
    float xh = xgp[(size_t)(up + 2 * UU)  * BB + b];

    float z   = 1.f / (1.f + expf(-(xz + hz)));
    float r   = 1.f / (1.f + expf(-(xr + hr)));
    float cnd = tanhf(xh + r * hc);
    float hprev = hR[up * BB + b];
    float hnew  = z * hprev + (1.f - z) * cnd;
    bool  m     = (t < seqlen[b]);
    hnew = m ? hnew : hprev;

    hW[up * BB + b] = hnew;
    hid[((size_t)b * TT + t) * 700 + dir * UU + up] = hnew;
}

// Final projections + 2-class softmax. One wave per (b,t) row.
__global__ __launch_bounds__(256) void proj_kernel(
    const float* __restrict__ Wz, const float* __restrict__ Wq,
    const float* __restrict__ hid, float* __restrict__ zT, float* __restrict__ zS)
{
    const int wave = threadIdx.x >> 6;
    const int lane = threadIdx.x & 63;
    const int row  = blockIdx.x * 4 + wave;     // row = b*T + t
    const float* hp = hid + (size_t)row * 700;
    float a0 = 0.f, a1 = 0.f, a2 = 0.f, a3 = 0.f;
    #pragma unroll
    for (int i = 0; i < 11; ++i) {
        int j = i * 64 + lane;
        if (j < 700) {
            float hv = hp[j];
            a0 = fmaf(hv, Wz[j], a0);
            a1 = fmaf(hv, Wz[700 + j], a1);
            a2 = fmaf(hv, Wq[j], a2);
            a3 = fmaf(hv, Wq[700 + j], a3);
        }
    }
    #pragma unroll
    for (int off = 32; off; off >>= 1) {
        a0 += __shfl_xor(a0, off, 64);
        a1 += __shfl_xor(a1, off, 64);
        a2 += __shfl_xor(a2, off, 64);
        a3 += __shfl_xor(a3, off, 64);
    }
    if (lane == 0) {
        float m1 = fmaxf(a0, a1);
        float e0 = expf(a0 - m1), e1 = expf(a1 - m1);
        float s1 = e0 + e1;
        zT[(size_t)row * 2]     = e0 / s1;
        zT[(size_t)row * 2 + 1] = e1 / s1;
        float m2 = fmaxf(a2, a3);
        float f0 = expf(a2 - m2), f1 = expf(a3 - m2);
        float s2 = f0 + f1;
        zS[(size_t)row * 2]     = f0 / s2;
        zS[(size_t)row * 2 + 1] = f1 / s2;
    }
}

extern "C" void kernel_launch(void* const* d_in, const int* in_sizes, int n_in,
                              void* d_out, int out_size, void* d_ws, size_t ws_size,
                              hipStream_t stream)
{
    (void)in_sizes; (void)n_in; (void)out_size; (void)ws_size;
    const float* ce  = (const float*)d_in[0];   // char_embedding [64,512,50]
    const float* we  = (const float*)d_in[1];   // word_embedding [64,512,300]
    const int*   sl  = (const int*)d_in[2];     // sequence_length [64]
    // d_in[3] = mask (bool) -- recomputed from sequence_length instead
    const float* Wz  = (const float*)d_in[4];   // [2,700]
    const float* Wq  = (const float*)d_in[5];   // [2,700]
    const float* Wxf = (const float*)d_in[6];   // [350,1050]
    const float* Whf = (const float*)d_in[7];   // [350,1050]
    const float* bf  = (const float*)d_in[8];   // [2,1050]
    const float* Wxb = (const float*)d_in[9];
    const float* Whb = (const float*)d_in[10];
    const float* bb  = (const float*)d_in[11];

    float* out = (float*)d_out;
    float* zT  = out;                       // [64,512,2]
    float* zS  = out + (size_t)BB * TT * 2; // [64,512,2]
    float* hid = out + (size_t)2 * BB * TT * 2; // [64,512,700]

    char* ws = (char*)d_ws;
    float* hbuf = (float*)(ws + HBUF_OFF);
    float* WhT  = (float*)(ws + WHT_OFF);
    float* xg   = (float*)(ws + XG_OFF);

    // zero initial hidden state (ws is poisoned before every launch)
    hipMemsetAsync(hbuf, 0, HBUF_BYTES, stream);
    wht_kernel<<<dim3((2 * UU * GG + 255) / 256), 256, 0, stream>>>(Whf, Whb, WhT);

    for (int c = 0; c < NCH; ++c) {
        xg_gemm_kernel<<<dim3(17, CT, 2), 256, 0, stream>>>(ce, we, Wxf, Wxb, bf, bb, xg, c);
        for (int s = c * CT; s < (c + 1) * CT; ++s) {
            gru_step_kernel<<<dim3(88, 2), 256, 0, stream>>>(xg, WhT, bf, bb, sl, hbuf, hid, s, c);
        }
    }
    proj_kernel<<<dim3(BB * TT / 4), 256, 0, stream>>>(Wz, Wq, hid, zT, zS);
}